// Round 1
// baseline (281.667 us; speedup 1.0000x reference)
//
#include <hip/hip_runtime.h>
#include <math.h>

// QLSTM: 12-qubit statevector sim, 16 timesteps x 4 gates x 64 samples.
// Index convention (matches jnp C-order flatten): qubit q <-> bit (11-q),
// i.e. qubit q has stride 2^(11-q) in the flat 4096-amp state.

// Composite permutation of CNOT ring layer 0 (r=1): new[i] = old[sigma0(i)].
// Derived from inverse prefix-XOR; verified on basis states |q0>,|q1>,|q11>.
__device__ __forceinline__ int sigma0(int w) {
    int r = w ^ (w >> 1);
    r ^= (w & 1) ? 0xC00 : 0;
    return r;
}
// CNOT ring layer 1 (r=2): two interleaved 6-bit chains (even/odd qubits).
// Verified on |q0>,|q1>,|q10>.
__device__ __forceinline__ int sigma1(int w) {
    int r = w ^ (w >> 2);
    r ^= (w & 2) ? 0xA00 : 0;
    r ^= (w & 1) ? 0x500 : 0;
    return r;
}

// Apply 4 Rot gates (one per local virtual qubit, strides 8,4,2,1 in j) to
// 16 register-resident amplitudes. m4 = 4 gates x 8 floats (row-major 2x2 cplx).
__device__ __forceinline__ void rot4(float ar[16], float ai[16],
                                     const float* __restrict__ m4) {
#pragma unroll
    for (int k = 0; k < 4; ++k) {
        const float g0r = m4[k*8+0], g0i = m4[k*8+1];
        const float g1r = m4[k*8+2], g1i = m4[k*8+3];
        const float g2r = m4[k*8+4], g2i = m4[k*8+5];
        const float g3r = m4[k*8+6], g3i = m4[k*8+7];
        const int vs = 8 >> k;
#pragma unroll
        for (int p = 0; p < 8; ++p) {
            const int lowm = vs - 1;
            const int j0 = ((p & ~lowm) << 1) | (p & lowm);
            const int j1 = j0 | vs;
            const float a0r = ar[j0], a0i = ai[j0];
            const float a1r = ar[j1], a1i = ai[j1];
            ar[j0] = g0r*a0r - g0i*a0i + g1r*a1r - g1i*a1i;
            ai[j0] = g0r*a0i + g0i*a0r + g1r*a1i + g1i*a1r;
            ar[j1] = g2r*a0r - g2i*a0i + g3r*a1r - g3i*a1i;
            ai[j1] = g2r*a0i + g2i*a0r + g3r*a1i + g3i*a1r;
        }
    }
}

// One timestep: 256 WGs = (gate g in 0..3) x (sample b in 0..63).
// Recomputes h_t from gate-activation history in ws (no cross-WG sync).
__global__ __launch_bounds__(256)
void qlstm_step(const float* __restrict__ inputs,  // (16,64,8)
                const float* __restrict__ wf, const float* __restrict__ wi,
                const float* __restrict__ wu, const float* __restrict__ wo,
                const float* __restrict__ fW, const float* __restrict__ fb,
                const float* __restrict__ iW, const float* __restrict__ ib,
                const float* __restrict__ uW, const float* __restrict__ ub,
                const float* __restrict__ oW, const float* __restrict__ ob,
                float* __restrict__ gact,   // ws: (16,4,64,4)
                float* __restrict__ out,    // (16*64*4) + hx(256) + cx(256)
                int t)
{
    __shared__ float2 st[4096];      // statevector
    __shared__ float rotm[24 * 8];   // 2 layers x 12 Rot gates x 8 floats
    __shared__ float rxc[12], rxs[12];
    __shared__ float hprev[4];
    __shared__ float zredw[4 * 12];
    __shared__ float zfin[12];

    const int tid = threadIdx.x;
    const int b = blockIdx.x & 63;
    const int g = blockIdx.x >> 6;

    const float* wsel = (g == 0) ? wf : (g == 1) ? wi : (g == 2) ? wu : wo;
    const float* Wsel = (g == 0) ? fW : (g == 1) ? iW : (g == 2) ? uW : oW;
    const float* bsel = (g == 0) ? fb : (g == 1) ? ib : (g == 2) ? ub : ob;

    // ---- h_t from stored gate activations (c,h chain). Threads 0..3 = h idx.
    if (tid < 4) {
        float c = 0.f, hh = 0.f;
        for (int s = 0; s < t; ++s) {
            const float* ga = gact + s * 1024 + b * 4 + tid;
            const float f_ = ga[0], i_ = ga[256], g_ = ga[512], o_ = ga[768];
            c = f_ * c + i_ * g_;
            hh = o_ * tanhf(c);
        }
        hprev[tid] = hh;
        if (g == 0 && t > 0) out[(t - 1) * 256 + b * 4 + tid] = hh;
    }
    // ---- Rot matrices for this gate-type (sample-independent), 24 threads.
    if (tid >= 32 && tid < 56) {
        const int k = tid - 32;                 // k = l*12 + qubit
        const float phi = wsel[k*3+0], th = wsel[k*3+1], om = wsel[k*3+2];
        float ct, sth; sincosf(0.5f * th, &sth, &ct);
        float ca, sa;  sincosf(0.5f * (phi + om), &sa, &ca);
        float cb, sb;  sincosf(0.5f * (phi - om), &sb, &cb);
        float* m = rotm + k * 8;
        m[0] =  ca * ct;  m[1] = -sa * ct;    // m00 = e^{-i a} c
        m[2] = -cb * sth; m[3] = -sb * sth;   // m01 = -e^{+i b} s
        m[4] =  cb * sth; m[5] = -sb * sth;   // m10 = e^{-i b} s
        m[6] =  ca * ct;  m[7] =  sa * ct;    // m11 = e^{+i a} c
    }
    __syncthreads();
    // ---- RX params: angle q<8 from x_t, else from h_t.
    if (tid < 12) {
        const float ang = (tid < 8) ? inputs[t * 512 + b * 8 + tid]
                                    : hprev[tid - 8];
        sincosf(0.5f * ang, &rxs[tid], &rxc[tid]);
    }
    __syncthreads();

    float ar[16], ai[16];
    const int base = tid << 4;

    // ---- Pass A0: build post-RX product state directly + Rot L0 on q8..11.
    {
        float rb = 1.f; int kb = 0;
#pragma unroll
        for (int q = 0; q < 8; ++q) {
            const int bit = (tid >> (7 - q)) & 1;
            rb *= bit ? rxs[q] : rxc[q];
            kb += bit;
        }
#pragma unroll
        for (int j = 0; j < 16; ++j) {
            float r = rb;
            r *= (j & 8) ? rxs[8]  : rxc[8];
            r *= (j & 4) ? rxs[9]  : rxc[9];
            r *= (j & 2) ? rxs[10] : rxc[10];
            r *= (j & 1) ? rxs[11] : rxc[11];
            const int k = (kb + __popc(j)) & 3;   // phase (-i)^k
            ar[j] = (k == 0) ? r : (k == 2) ? -r : 0.f;
            ai[j] = (k == 1) ? -r : (k == 3) ? r : 0.f;
        }
        rot4(ar, ai, rotm + 8 * 8);               // layer0 q8..11
#pragma unroll
        for (int j = 0; j < 16; ++j) st[base + j] = make_float2(ar[j], ai[j]);
    }
    __syncthreads();

    // ---- Pass B0: Rot L0 on q4..7 (j stride 16).
    {
        const int ib0 = ((tid >> 4) << 8) | (tid & 15);
#pragma unroll
        for (int j = 0; j < 16; ++j) { float2 v = st[ib0 + j*16]; ar[j]=v.x; ai[j]=v.y; }
        rot4(ar, ai, rotm + 4 * 8);
#pragma unroll
        for (int j = 0; j < 16; ++j) st[ib0 + j*16] = make_float2(ar[j], ai[j]);
    }
    __syncthreads();

    // ---- Pass C0: Rot L0 on q0..3 (j stride 256).
    {
#pragma unroll
        for (int j = 0; j < 16; ++j) { float2 v = st[tid + j*256]; ar[j]=v.x; ai[j]=v.y; }
        rot4(ar, ai, rotm + 0 * 8);
#pragma unroll
        for (int j = 0; j < 16; ++j) st[tid + j*256] = make_float2(ar[j], ai[j]);
    }
    __syncthreads();

    // ---- Pass A1: CNOT ring L0 (gather sigma0) + Rot L1 q8..11.
    {
#pragma unroll
        for (int j = 0; j < 16; ++j) { float2 v = st[sigma0(base + j)]; ar[j]=v.x; ai[j]=v.y; }
        rot4(ar, ai, rotm + (12 + 8) * 8);
        __syncthreads();                          // all gathers done before overwrite
#pragma unroll
        for (int j = 0; j < 16; ++j) st[base + j] = make_float2(ar[j], ai[j]);
    }
    __syncthreads();

    // ---- Pass B1: Rot L1 q4..7.
    {
        const int ib0 = ((tid >> 4) << 8) | (tid & 15);
#pragma unroll
        for (int j = 0; j < 16; ++j) { float2 v = st[ib0 + j*16]; ar[j]=v.x; ai[j]=v.y; }
        rot4(ar, ai, rotm + (12 + 4) * 8);
#pragma unroll
        for (int j = 0; j < 16; ++j) st[ib0 + j*16] = make_float2(ar[j], ai[j]);
    }
    __syncthreads();

    // ---- Pass C1: Rot L1 q0..3.
    {
#pragma unroll
        for (int j = 0; j < 16; ++j) { float2 v = st[tid + j*256]; ar[j]=v.x; ai[j]=v.y; }
        rot4(ar, ai, rotm + 12 * 8);
#pragma unroll
        for (int j = 0; j < 16; ++j) st[tid + j*256] = make_float2(ar[j], ai[j]);
    }
    __syncthreads();

    // ---- Expvals: CNOT ring L1 fused as gather sigma1; z_q = sum +-|amp|^2.
    float S = 0.f, z8 = 0.f, z9 = 0.f, z10 = 0.f, z11 = 0.f;
#pragma unroll
    for (int j = 0; j < 16; ++j) {
        const float2 v = st[sigma1(base + j)];
        const float p = v.x * v.x + v.y * v.y;
        S += p;
        z8  += (j & 8) ? -p : p;
        z9  += (j & 4) ? -p : p;
        z10 += (j & 2) ? -p : p;
        z11 += (j & 1) ? -p : p;
    }
    float zq[12];
#pragma unroll
    for (int q = 0; q < 8; ++q)
        zq[q] = ((tid >> (7 - q)) & 1) ? -S : S;  // qubits 0..7: sign fixed per thread
    zq[8] = z8; zq[9] = z9; zq[10] = z10; zq[11] = z11;

    const int lane = tid & 63, wv = tid >> 6;
#pragma unroll
    for (int q = 0; q < 12; ++q) {
        float v = zq[q];
#pragma unroll
        for (int off = 32; off > 0; off >>= 1) v += __shfl_down(v, off);
        if (lane == 0) zredw[wv * 12 + q] = v;
    }
    __syncthreads();
    if (tid < 12)
        zfin[tid] = zredw[tid] + zredw[12 + tid] + zredw[24 + tid] + zredw[36 + tid];
    __syncthreads();

    // ---- Linear head + nonlinearity; write gate activation to history.
    if (tid < 4) {
        float acc = bsel[tid];
#pragma unroll
        for (int q = 0; q < 12; ++q) acc += Wsel[tid * 12 + q] * zfin[q];
        const float act = (g == 2) ? tanhf(acc) : 1.f / (1.f + expf(-acc));
        gact[t * 1024 + g * 256 + b * 4 + tid] = act;
    }
}

// Final chain: outputs[15], hx, cx.
__global__ __launch_bounds__(256)
void qlstm_final(const float* __restrict__ gact, float* __restrict__ out) {
    const int tid = threadIdx.x;    // tid = b*4 + h
    float c = 0.f, hh = 0.f;
    for (int s = 0; s < 16; ++s) {
        const float* ga = gact + s * 1024 + tid;
        const float f_ = ga[0], i_ = ga[256], g_ = ga[512], o_ = ga[768];
        c = f_ * c + i_ * g_;
        hh = o_ * tanhf(c);
    }
    out[3840 + tid] = hh;   // outputs[15]
    out[4096 + tid] = hh;   // hx
    out[4352 + tid] = c;    // cx
}

extern "C" void kernel_launch(void* const* d_in, const int* in_sizes, int n_in,
                              void* d_out, int out_size, void* d_ws, size_t ws_size,
                              hipStream_t stream) {
    (void)in_sizes; (void)n_in; (void)out_size; (void)ws_size;
    const float* inputs = (const float*)d_in[0];
    const float* wf = (const float*)d_in[1];
    const float* wi = (const float*)d_in[2];
    const float* wu = (const float*)d_in[3];
    const float* wo = (const float*)d_in[4];
    const float* fW = (const float*)d_in[5];
    const float* fb = (const float*)d_in[6];
    const float* iW = (const float*)d_in[7];
    const float* ib = (const float*)d_in[8];
    const float* uW = (const float*)d_in[9];
    const float* ub = (const float*)d_in[10];
    const float* oW = (const float*)d_in[11];
    const float* ob = (const float*)d_in[12];
    float* out = (float*)d_out;
    float* gact = (float*)d_ws;   // 16*4*64*4 floats = 16 KB

    for (int t = 0; t < 16; ++t)
        qlstm_step<<<256, 256, 0, stream>>>(inputs, wf, wi, wu, wo,
                                            fW, fb, iW, ib, uW, ub, oW, ob,
                                            gact, out, t);
    qlstm_final<<<1, 256, 0, stream>>>(gact, out);
}

// Round 2
// 228.066 us; speedup vs baseline: 1.2350x; 1.2350x over previous
//
#include <hip/hip_runtime.h>
#include <math.h>

// QLSTM: 12-qubit statevector sim, 16 timesteps x 4 gates x 64 samples.
// Qubit q <-> bit (11-q) of the flat 4096-amp index (jnp C-order).
// LDS layout: split real/imag float arrays with XOR swizzle
//   phys = idx ^ ((idx>>4)&31)   (bijective; provably <=2 lanes/bank on the
//   A/B/C pass patterns and the sigma0 gather; sigma1 gather is 4-way).

__device__ __forceinline__ int swz(int i) { return i ^ ((i >> 4) & 31); }

// CNOT ring layer 0 (r=1) composite perm: new[i] = old[sigma0(i)].
__device__ __forceinline__ int sigma0(int w) {
    int r = w ^ (w >> 1);
    r ^= (w & 1) ? 0xC00 : 0;
    return r;
}
// CNOT ring layer 1 (r=2).
__device__ __forceinline__ int sigma1(int w) {
    int r = w ^ (w >> 2);
    r ^= (w & 2) ? 0xA00 : 0;
    r ^= (w & 1) ? 0x500 : 0;
    return r;
}

__device__ __forceinline__ float ftanh(float x) {
    x = fminf(fmaxf(x, -15.f), 15.f);
    const float e = __expf(2.f * x);
    return (e - 1.f) / (e + 1.f);
}
__device__ __forceinline__ float fsigm(float x) {
    return 1.f / (1.f + __expf(-x));
}

// Apply 4 Rot gates (strides 8,4,2,1 in j) to 16 register-resident amps.
__device__ __forceinline__ void rot4(float ar[16], float ai[16],
                                     const float* __restrict__ m4) {
#pragma unroll
    for (int k = 0; k < 4; ++k) {
        const float g0r = m4[k*8+0], g0i = m4[k*8+1];
        const float g1r = m4[k*8+2], g1i = m4[k*8+3];
        const float g2r = m4[k*8+4], g2i = m4[k*8+5];
        const float g3r = m4[k*8+6], g3i = m4[k*8+7];
        const int vs = 8 >> k;
#pragma unroll
        for (int p = 0; p < 8; ++p) {
            const int lowm = vs - 1;
            const int j0 = ((p & ~lowm) << 1) | (p & lowm);
            const int j1 = j0 | vs;
            const float a0r = ar[j0], a0i = ai[j0];
            const float a1r = ar[j1], a1i = ai[j1];
            ar[j0] = g0r*a0r - g0i*a0i + g1r*a1r - g1i*a1i;
            ai[j0] = g0r*a0i + g0i*a0r + g1r*a1i + g1i*a1r;
            ar[j1] = g2r*a0r - g2i*a0i + g3r*a1r - g3i*a1i;
            ai[j1] = g2r*a0i + g2i*a0r + g3r*a1i + g3i*a1r;
        }
    }
}

// One timestep: 256 WGs = (gate g) x (sample b).
// gact: 2-slot ring [2][4][64][4]; cst: 2-slot ring [2][64][4].
__global__ __launch_bounds__(256)
void qlstm_step(const float* __restrict__ inputs,  // (16,64,8)
                const float* __restrict__ wf, const float* __restrict__ wi,
                const float* __restrict__ wu, const float* __restrict__ wo,
                const float* __restrict__ fW, const float* __restrict__ fb,
                const float* __restrict__ iW, const float* __restrict__ ib,
                const float* __restrict__ uW, const float* __restrict__ ub,
                const float* __restrict__ oW, const float* __restrict__ ob,
                float* __restrict__ gact, float* __restrict__ cst,
                float* __restrict__ out, int t)
{
    __shared__ float str[4096], sti[4096];
    __shared__ float rotm[24 * 8];
    __shared__ float rxc[12], rxs[12];
    __shared__ float zredw[4 * 12];
    __shared__ float zfin[12];

    const int tid = threadIdx.x;
    const int b = blockIdx.x & 63;
    const int g = blockIdx.x >> 6;

    const float* wsel = (g == 0) ? wf : (g == 1) ? wi : (g == 2) ? wu : wo;
    const float* Wsel = (g == 0) ? fW : (g == 1) ? iW : (g == 2) ? uW : oW;
    const float* bsel = (g == 0) ? fb : (g == 1) ? ib : (g == 2) ? ub : ob;

    // ---- O(1) recurrence: c_{t-1},h_{t-1} from step t-1 activations. ----
    if (tid < 4) {
        float hh = 0.f;
        if (t > 0) {
            const float* ga = gact + ((t - 1) & 1) * 1024 + b * 4 + tid;
            const float f_ = ga[0], i_ = ga[256], g_ = ga[512], o_ = ga[768];
            const float cold = (t > 1) ? cst[((t - 2) & 1) * 256 + b * 4 + tid] : 0.f;
            const float cnew = f_ * cold + i_ * g_;
            hh = o_ * ftanh(cnew);
            cst[((t - 1) & 1) * 256 + b * 4 + tid] = cnew;   // 4 same-value writers
            if (g == 0) out[(t - 1) * 256 + b * 4 + tid] = hh;
        }
        __sincosf(0.5f * hh, &rxs[8 + tid], &rxc[8 + tid]);  // RX for q8..11
    } else if (tid >= 96 && tid < 104) {                     // RX for q0..7
        const int q = tid - 96;
        __sincosf(0.5f * inputs[t * 512 + b * 8 + q], &rxs[q], &rxc[q]);
    } else if (tid >= 64 && tid < 88) {                      // Rot matrices
        const int k = tid - 64;                              // l*12 + qubit
        const float phi = wsel[k*3+0], th = wsel[k*3+1], om = wsel[k*3+2];
        float ct, sth; __sincosf(0.5f * th, &sth, &ct);
        float ca, sa;  __sincosf(0.5f * (phi + om), &sa, &ca);
        float cb, sb;  __sincosf(0.5f * (phi - om), &sb, &cb);
        float* m = rotm + k * 8;
        m[0] =  ca * ct;  m[1] = -sa * ct;
        m[2] = -cb * sth; m[3] = -sb * sth;
        m[4] =  cb * sth; m[5] = -sb * sth;
        m[6] =  ca * ct;  m[7] =  sa * ct;
    }
    __syncthreads();

    float ar[16], ai[16];
    const int base = tid << 4;
    const int aBase = base ^ (tid & 16);   // swz(base+j) = aBase + (j^aMsk)
    const int aMsk = tid & 15;

    // ---- A0: post-RX product state in regs + Rot L0 q8..11. ----
    {
        float rb = 1.f; int kb = 0;
#pragma unroll
        for (int q = 0; q < 8; ++q) {
            const int bit = (tid >> (7 - q)) & 1;
            rb *= bit ? rxs[q] : rxc[q];
            kb += bit;
        }
#pragma unroll
        for (int j = 0; j < 16; ++j) {
            float r = rb;
            r *= (j & 8) ? rxs[8]  : rxc[8];
            r *= (j & 4) ? rxs[9]  : rxc[9];
            r *= (j & 2) ? rxs[10] : rxc[10];
            r *= (j & 1) ? rxs[11] : rxc[11];
            const int k = (kb + __popc(j)) & 3;     // phase (-i)^k
            ar[j] = (k == 0) ? r : (k == 2) ? -r : 0.f;
            ai[j] = (k == 1) ? -r : (k == 3) ? r : 0.f;
        }
        rot4(ar, ai, rotm + 64);
#pragma unroll
        for (int j = 0; j < 16; ++j) {
            const int a = aBase + (j ^ aMsk);
            str[a] = ar[j]; sti[a] = ai[j];
        }
    }
    __syncthreads();

    // ---- B0: Rot L0 q4..7 (stride 16). ----
    {
        const int ib0 = ((tid >> 4) << 8) | (tid & 15);
        int adr[16];
#pragma unroll
        for (int j = 0; j < 16; ++j) {
            adr[j] = swz(ib0 + (j << 4));
            ar[j] = str[adr[j]]; ai[j] = sti[adr[j]];
        }
        rot4(ar, ai, rotm + 32);
#pragma unroll
        for (int j = 0; j < 16; ++j) { str[adr[j]] = ar[j]; sti[adr[j]] = ai[j]; }
    }
    __syncthreads();

    // ---- C0: Rot L0 q0..3 (stride 256). ----
    {
        int adr[16];
#pragma unroll
        for (int j = 0; j < 16; ++j) {
            adr[j] = swz(tid + (j << 8));
            ar[j] = str[adr[j]]; ai[j] = sti[adr[j]];
        }
        rot4(ar, ai, rotm + 0);
#pragma unroll
        for (int j = 0; j < 16; ++j) { str[adr[j]] = ar[j]; sti[adr[j]] = ai[j]; }
    }
    __syncthreads();

    // ---- A1: gather sigma0 (CNOT ring L0) + Rot L1 q8..11. ----
    {
#pragma unroll
        for (int j = 0; j < 16; ++j) {
            const int a = swz(sigma0(base + j));
            ar[j] = str[a]; ai[j] = sti[a];
        }
        rot4(ar, ai, rotm + 160);
        __syncthreads();                     // gathers done before overwrite
#pragma unroll
        for (int j = 0; j < 16; ++j) {
            const int a = aBase + (j ^ aMsk);
            str[a] = ar[j]; sti[a] = ai[j];
        }
    }
    __syncthreads();

    // ---- B1: Rot L1 q4..7. ----
    {
        const int ib0 = ((tid >> 4) << 8) | (tid & 15);
        int adr[16];
#pragma unroll
        for (int j = 0; j < 16; ++j) {
            adr[j] = swz(ib0 + (j << 4));
            ar[j] = str[adr[j]]; ai[j] = sti[adr[j]];
        }
        rot4(ar, ai, rotm + 128);
#pragma unroll
        for (int j = 0; j < 16; ++j) { str[adr[j]] = ar[j]; sti[adr[j]] = ai[j]; }
    }
    __syncthreads();

    // ---- C1: Rot L1 q0..3. ----
    {
        int adr[16];
#pragma unroll
        for (int j = 0; j < 16; ++j) {
            adr[j] = swz(tid + (j << 8));
            ar[j] = str[adr[j]]; ai[j] = sti[adr[j]];
        }
        rot4(ar, ai, rotm + 96);
#pragma unroll
        for (int j = 0; j < 16; ++j) { str[adr[j]] = ar[j]; sti[adr[j]] = ai[j]; }
    }
    __syncthreads();

    // ---- Expvals: CNOT ring L1 fused as gather sigma1. ----
    float S = 0.f, z8 = 0.f, z9 = 0.f, z10 = 0.f, z11 = 0.f;
#pragma unroll
    for (int j = 0; j < 16; ++j) {
        const int a = swz(sigma1(base + j));
        const float vr = str[a], vi = sti[a];
        const float p = vr * vr + vi * vi;
        S += p;
        z8  += (j & 8) ? -p : p;
        z9  += (j & 4) ? -p : p;
        z10 += (j & 2) ? -p : p;
        z11 += (j & 1) ? -p : p;
    }
    float zq[12];
#pragma unroll
    for (int q = 0; q < 8; ++q)
        zq[q] = ((tid >> (7 - q)) & 1) ? -S : S;
    zq[8] = z8; zq[9] = z9; zq[10] = z10; zq[11] = z11;

    const int lane = tid & 63, wv = tid >> 6;
#pragma unroll
    for (int q = 0; q < 12; ++q) {
        float v = zq[q];
#pragma unroll
        for (int off = 32; off > 0; off >>= 1) v += __shfl_down(v, off);
        if (lane == 0) zredw[wv * 12 + q] = v;
    }
    __syncthreads();
    if (tid < 12)
        zfin[tid] = zredw[tid] + zredw[12 + tid] + zredw[24 + tid] + zredw[36 + tid];
    __syncthreads();

    // ---- Linear head + activation -> gact ring. ----
    if (tid < 4) {
        float acc = bsel[tid];
#pragma unroll
        for (int q = 0; q < 12; ++q) acc += Wsel[tid * 12 + q] * zfin[q];
        const float act = (g == 2) ? ftanh(acc) : fsigm(acc);
        gact[(t & 1) * 1024 + g * 256 + b * 4 + tid] = act;
    }
}

// Final: out[15], hx, cx from step-15 activations + c after step 14.
__global__ __launch_bounds__(256)
void qlstm_final(const float* __restrict__ gact, const float* __restrict__ cst,
                 float* __restrict__ out) {
    const int tid = threadIdx.x;   // b*4 + h
    const float* ga = gact + 1024 + tid;          // slot 15&1 = 1
    const float f_ = ga[0], i_ = ga[256], g_ = ga[512], o_ = ga[768];
    const float cold = cst[tid];                  // slot (15-1)&1 = 0
    const float cnew = f_ * cold + i_ * g_;
    const float hh = o_ * ftanh(cnew);
    out[3840 + tid] = hh;   // outputs[15]
    out[4096 + tid] = hh;   // hx
    out[4352 + tid] = cnew; // cx
}

extern "C" void kernel_launch(void* const* d_in, const int* in_sizes, int n_in,
                              void* d_out, int out_size, void* d_ws, size_t ws_size,
                              hipStream_t stream) {
    (void)in_sizes; (void)n_in; (void)out_size; (void)ws_size;
    const float* inputs = (const float*)d_in[0];
    const float* wf = (const float*)d_in[1];
    const float* wi = (const float*)d_in[2];
    const float* wu = (const float*)d_in[3];
    const float* wo = (const float*)d_in[4];
    const float* fW = (const float*)d_in[5];
    const float* fb = (const float*)d_in[6];
    const float* iW = (const float*)d_in[7];
    const float* ib = (const float*)d_in[8];
    const float* uW = (const float*)d_in[9];
    const float* ub = (const float*)d_in[10];
    const float* oW = (const float*)d_in[11];
    const float* ob = (const float*)d_in[12];
    float* out = (float*)d_out;
    float* gact = (float*)d_ws;          // 2*1024 floats
    float* cst  = (float*)d_ws + 2048;   // 2*256 floats

    for (int t = 0; t < 16; ++t)
        qlstm_step<<<256, 256, 0, stream>>>(inputs, wf, wi, wu, wo,
                                            fW, fb, iW, ib, uW, ub, oW, ob,
                                            gact, cst, out, t);
    qlstm_final<<<1, 256, 0, stream>>>(gact, cst, out);
}